// Round 1
// 718.529 us; speedup vs baseline: 1.0025x; 1.0025x over previous
//
#include <hip/hip_runtime.h>
#include <stdint.h>

// One wave (64 lanes) per row. 512 neighbors -> 8 per lane, processed with
// per-lane ONLINE softmax (flash-style) so the 64-reg x[8][8] buffer is gone.
// Block = 256 threads = 4 waves = 4 rows. All fp32, mask int32.
// __launch_bounds__(256, 6): 6 waves/EU min -> VGPR cap ~84 (hand-count ~65).
__global__ __launch_bounds__(256, 6) void gat_kernel(
    const float* __restrict__ ego,      // B x 8
    const float* __restrict__ neigh,    // B x 512 x 8
    const int*   __restrict__ mask,     // B x 512 (0/1)
    const float* __restrict__ W_ego,    // 8 x 8
    const float* __restrict__ b_ego,    // 8
    const float* __restrict__ w_attn,   // 16
    const float* __restrict__ b_attn,   // 1
    const float* __restrict__ W_out,    // 8 x 32
    const float* __restrict__ b_out,    // 32
    float* __restrict__ out,            // B x 32
    int B)
{
    const int lane = threadIdx.x & 63;
    const int row  = (blockIdx.x << 2) + (threadIdx.x >> 6);
    if (row >= B) return;

    // ---- per-row uniform attention bias: e = (ego @ W_ego + b_ego) . wa_e + b_attn
    float e = b_attn[0];
    #pragma unroll
    for (int fp = 0; fp < 8; ++fp) {
        float ep = b_ego[fp];
        #pragma unroll
        for (int f = 0; f < 8; ++f)
            ep = fmaf(ego[row * 8 + f], W_ego[f * 8 + fp], ep);
        e = fmaf(ep, w_attn[fp], e);
    }

    float wn[8];
    #pragma unroll
    for (int f = 0; f < 8; ++f) wn[f] = w_attn[8 + f];

    // neighbor row = 8 floats = 2 float4s; lane handles n = j*64 + lane (coalesced)
    const float4* __restrict__ nrow = (const float4*)(neigh + (size_t)row * (512 * 8));
    const int*    __restrict__ mrow = mask + (size_t)row * 512;

    // ---- online-softmax state (per lane)
    float m = -1.0e9f;          // running max (matches masked-score sentinel)
    float Z = 0.0f;             // running denominator
    float agg[8] = {0.f, 0.f, 0.f, 0.f, 0.f, 0.f, 0.f, 0.f};

    // ---- 2-deep prefetch
    float4 a0 = nrow[2 * lane];
    float4 b0 = nrow[2 * lane + 1];
    int    v0 = mrow[lane];
    float4 a1 = nrow[2 * (64 + lane)];
    float4 b1 = nrow[2 * (64 + lane) + 1];
    int    v1 = mrow[64 + lane];

    #pragma unroll
    for (int j = 0; j < 8; ++j) {
        const float4 a = a0; const float4 b = b0; const int vv = v0;
        a0 = a1; b0 = b1; v0 = v1;
        if (j < 6) {                       // compile-time resolved (full unroll)
            const int n = ((j + 2) << 6) + lane;
            a1 = nrow[2 * n];
            b1 = nrow[2 * n + 1];
            v1 = mrow[n];
        }

        const float xf[8] = {a.x, a.y, a.z, a.w, b.x, b.y, b.z, b.w};
        float d = e;
        #pragma unroll
        for (int f = 0; f < 8; ++f) d = fmaf(xf[f], wn[f], d);
        const float s = vv ? d : -1.0e9f;

        // branchless online update:
        //  - m unchanged -> c = expf(0) = 1 exactly (no drift)
        //  - first valid score -> c = expf(-huge) = 0 (flushes the empty state)
        //  - invalid neighbor  -> w forced to 0 (matches reference mask semantics)
        const float mn = fmaxf(m, s);
        const float c  = __expf(m - mn);
        const float w  = vv ? __expf(s - mn) : 0.0f;
        Z = fmaf(Z, c, w);
        #pragma unroll
        for (int f = 0; f < 8; ++f) agg[f] = fmaf(agg[f], c, w * xf[f]);
        m = mn;
    }

    // ---- cross-lane log-sum-exp butterfly merge (all lanes end with the result)
    #pragma unroll
    for (int off = 32; off > 0; off >>= 1) {
        const float m2 = __shfl_xor(m, off);
        const float Z2 = __shfl_xor(Z, off);
        float ag2[8];
        #pragma unroll
        for (int f = 0; f < 8; ++f) ag2[f] = __shfl_xor(agg[f], off);
        const float mn = fmaxf(m, m2);
        const float c1 = __expf(m - mn);   // both halves all-masked: c1=c2=1, Z stays 0
        const float c2 = __expf(m2 - mn);
        Z = Z * c1 + Z2 * c2;
        #pragma unroll
        for (int f = 0; f < 8; ++f) agg[f] = agg[f] * c1 + ag2[f] * c2;
        m = mn;
    }

    // all-masked row => Z == 0 exactly => agg = 0 => out = b_out (matches reference)
    const float inv = (Z > 0.0f) ? (1.0f / Z) : 0.0f;

    // ---- output projection: lanes 0..31 each produce one of the 32 outputs
    if (lane < 32) {
        float o = b_out[lane];
        #pragma unroll
        for (int f = 0; f < 8; ++f)
            o = fmaf(agg[f] * inv, W_out[f * 32 + lane], o);
        out[(size_t)row * 32 + lane] = o;
    }
}

extern "C" void kernel_launch(void* const* d_in, const int* in_sizes, int n_in,
                              void* d_out, int out_size, void* d_ws, size_t ws_size,
                              hipStream_t stream) {
    const float* ego    = (const float*)d_in[0];
    const float* neigh  = (const float*)d_in[1];
    const int*   mask   = (const int*)d_in[2];
    const float* W_ego  = (const float*)d_in[3];
    const float* b_ego  = (const float*)d_in[4];
    const float* w_attn = (const float*)d_in[5];
    const float* b_attn = (const float*)d_in[6];
    const float* W_out  = (const float*)d_in[7];
    const float* b_out  = (const float*)d_in[8];
    float* out = (float*)d_out;

    const int B = in_sizes[0] / 8;     // 32768
    const int grid = (B + 3) / 4;      // 4 rows per 256-thread block

    gat_kernel<<<grid, 256, 0, stream>>>(ego, neigh, mask, W_ego, b_ego,
                                         w_attn, b_attn, W_out, b_out, out, B);
}